// Round 3
// baseline (390.200 us; speedup 1.0000x reference)
//
#include <hip/hip_runtime.h>

#define BSZ 4
#define NH 16
#define SL 1024
#define DH 64

typedef __bf16 bf16x8 __attribute__((ext_vector_type(8)));
typedef float  f32x4  __attribute__((ext_vector_type(4)));

static __device__ __forceinline__ __bf16 f2bf(float f) {
    return (__bf16)f;                          // HW RNE f32->bf16 cvt
}

static __device__ __forceinline__ void mfma16(f32x4& d, bf16x8 a, bf16x8 b) {
    d = __builtin_amdgcn_mfma_f32_16x16x32_bf16(a, b, d, 0, 0, 0);
}

// Block: 4 waves / 256 threads. Handles 16 q-rows x full 1024 s-cols of one (b,h).
// Wave w owns s in [w*256, w*256+256).
// SWAPPED QK^T: acc[t] = mfma(K_frag, Q_frag) => D[m=s][n=q]; lane l15 = q,
// regs i=0..3 = s = t*16 + 4*lhi + i  (4 CONTIGUOUS s per lane -> float4 I/O on
// prev/scores/weights, and P regs feed PV's A-fragment directly, no LDS transpose).
__global__ void __launch_bounds__(256, 4)
attn_fused(const float* __restrict__ qg0, const float* __restrict__ kg0,
           const float* __restrict__ vg0, const float* __restrict__ pg0,
           const float* __restrict__ scale_p,
           float* __restrict__ og0, float* __restrict__ wg0, float* __restrict__ sg0)
{
    // LDS: q_s f32[16][68] @0 (4352B), aliased by o_s f32[4][16][68] @0 (17408B);
    //      red f32[2][4][16] @17408 (512B). Total 17920B.
    __shared__ __align__(16) char smem[17920];
    float (*q_s)[68]     = (float (*)[68])smem;
    float (*o_s)[16][68] = (float (*)[16][68])smem;
    float *red           = (float*)(smem + 17408);

    const int bid     = blockIdx.x;
    const int logical = (bid & 7) * 512 + (bid >> 3);   // XCD swizzle, bijective (4096%8==0)
    const int bh      = logical >> 6;                    // 64 q-tiles per (b,h)
    const int qbase   = (logical & 63) << 4;

    const int tid   = threadIdx.x;
    const int wid   = tid >> 6;
    const int lane  = tid & 63;
    const int l15   = lane & 15;
    const int lhi   = lane >> 4;
    const int sbase = wid << 8;          // this wave's s-range base

    const float scale = *scale_p;

    const float* qg = qg0 + (size_t)bh * SL * DH;
    const float* kg = kg0 + (size_t)bh * DH * SL;   // k is [d][s]
    const float* vg = vg0 + (size_t)bh * SL * DH;
    const float* pg = pg0 + (size_t)bh * SL * SL;
    float* og = og0 + (size_t)bh * SL * DH;
    float* wg = wg0 + (size_t)bh * SL * SL;
    float* sg = sg0 + (size_t)bh * SL * SL;

    // ---- stage Q tile (16x64 f32), coalesced float4 ----
    {
        const int r  = tid >> 4;
        const int c4 = (tid & 15) << 2;
        const float4 t = *(const float4*)(qg + (size_t)(qbase + r) * DH + c4);
        *(float4*)&q_s[r][c4] = t;
    }
    __syncthreads();

    // ---- Q fragments (B operand): B[k=d][n=q], lane l15 = q, k-map d ----
    bf16x8 qf[2];
#pragma unroll
    for (int ks = 0; ks < 2; ++ks)
#pragma unroll
        for (int j = 0; j < 8; ++j) {
            const int d = ks * 32 + 4 * lhi + (j & 3) + 16 * (j >> 2);
            qf[ks][j] = f2bf(q_s[l15][d]);
        }

    // ---- QK^T (swapped): acc[t][i] = S[s = sbase+t*16+4*lhi+i][q = qbase+l15] ----
    f32x4 acc[16];
#pragma unroll
    for (int t = 0; t < 16; ++t) { f32x4 z = {0.f, 0.f, 0.f, 0.f}; acc[t] = z; }

#pragma unroll
    for (int t = 0; t < 16; ++t) {
        const int s = sbase + t * 16 + l15;
#pragma unroll
        for (int ks = 0; ks < 2; ++ks) {
            bf16x8 kf;   // A[m=s][k=d], lane l15 = s
#pragma unroll
            for (int j = 0; j < 8; ++j) {
                const int d = ks * 32 + 4 * lhi + (j & 3) + 16 * (j >> 2);
                kf[j] = f2bf(kg[(size_t)d * SL + s]);   // 64B segments per 16 lanes
            }
            mfma16(acc[t], kf, qf[ks]);
        }
    }

    // ---- scores = acc*scale + prev (float4) ; write scores (float4) ----
    const int   qrow = qbase + l15;
    const float* pgr = pg + (size_t)qrow * SL;
    float*       sgr = sg + (size_t)qrow * SL;
    float*       wgr = wg + (size_t)qrow * SL;
#pragma unroll
    for (int t = 0; t < 16; ++t) {
        const int s0 = sbase + t * 16 + 4 * lhi;
        const float4 pv = *(const float4*)(pgr + s0);
        acc[t][0] = acc[t][0] * scale + pv.x;
        acc[t][1] = acc[t][1] * scale + pv.y;
        acc[t][2] = acc[t][2] * scale + pv.z;
        acc[t][3] = acc[t][3] * scale + pv.w;
        *(float4*)(sgr + s0) = make_float4(acc[t][0], acc[t][1], acc[t][2], acc[t][3]);
    }

    // ---- softmax over s (64 regs in-lane -> 2 shfl -> LDS cross-wave) ----
    float mx = acc[0][0];
#pragma unroll
    for (int t = 0; t < 16; ++t)
#pragma unroll
        for (int i = 0; i < 4; ++i) mx = fmaxf(mx, acc[t][i]);
    mx = fmaxf(mx, __shfl_xor(mx, 16, 64));
    mx = fmaxf(mx, __shfl_xor(mx, 32, 64));
    if (lhi == 0) red[wid * 16 + l15] = mx;
    __syncthreads();
    mx = fmaxf(fmaxf(red[0 + l15], red[16 + l15]),
               fmaxf(red[32 + l15], red[48 + l15]));

    float sm = 0.f;
#pragma unroll
    for (int t = 0; t < 16; ++t)
#pragma unroll
        for (int i = 0; i < 4; ++i) {
            const float p = __expf(acc[t][i] - mx);
            acc[t][i] = p;
            sm += p;
        }
    sm += __shfl_xor(sm, 16, 64);
    sm += __shfl_xor(sm, 32, 64);
    if (lhi == 0) red[64 + wid * 16 + l15] = sm;
    __syncthreads();
    const float inv = 1.f / (red[64 + l15] + red[64 + 16 + l15] +
                             red[64 + 32 + l15] + red[64 + 48 + l15]);

    // ---- weights: normalize in regs, float4 store ----
#pragma unroll
    for (int t = 0; t < 16; ++t) {
        const int s0 = sbase + t * 16 + 4 * lhi;
        acc[t][0] *= inv; acc[t][1] *= inv; acc[t][2] *= inv; acc[t][3] *= inv;
        *(float4*)(wgr + s0) = make_float4(acc[t][0], acc[t][1], acc[t][2], acc[t][3]);
    }

    // ---- PV: A-fragment comes straight from acc regs (no LDS transpose) ----
    // A[m=q][k=s]: af[j] = P[q=l15][s = sbase+ks*32+4*lhi+(j&3)+16*(j>>2)]
    //            = acc[2*ks + (j>>2)][j&3]
    f32x4 oacc[4];
#pragma unroll
    for (int nt = 0; nt < 4; ++nt) { f32x4 z = {0.f, 0.f, 0.f, 0.f}; oacc[nt] = z; }

#pragma unroll
    for (int ks = 0; ks < 8; ++ks) {
        bf16x8 af;
#pragma unroll
        for (int j = 0; j < 8; ++j) af[j] = f2bf(acc[2 * ks + (j >> 2)][j & 3]);
#pragma unroll
        for (int nt = 0; nt < 4; ++nt) {
            bf16x8 bf;   // B[k=s][n=dh], lane l15 = dh within tile nt
#pragma unroll
            for (int j = 0; j < 8; ++j) {
                const int s = sbase + ks * 32 + 4 * lhi + (j & 3) + 16 * (j >> 2);
                bf[j] = f2bf(vg[(size_t)s * DH + nt * 16 + l15]);
            }
            mfma16(oacc[nt], af, bf);
        }
    }

    // ---- cross-wave reduce of PV partials (o_s aliases q_s; q_s reads are
    //      long done — every wave passed the softmax barriers) ----
#pragma unroll
    for (int nt = 0; nt < 4; ++nt)
#pragma unroll
        for (int i = 0; i < 4; ++i)
            o_s[wid][4 * lhi + i][nt * 16 + l15] = oacc[nt][i];
    __syncthreads();
    {
        const int r  = tid >> 4;
        const int c4 = (tid & 15) << 2;
        float4 a = *(const float4*)&o_s[0][r][c4];
        const float4 b = *(const float4*)&o_s[1][r][c4];
        const float4 c = *(const float4*)&o_s[2][r][c4];
        const float4 d = *(const float4*)&o_s[3][r][c4];
        a.x += b.x + c.x + d.x;  a.y += b.y + c.y + d.y;
        a.z += b.z + c.z + d.z;  a.w += b.w + c.w + d.w;
        *(float4*)(og + (size_t)(qbase + r) * DH + c4) = a;
    }
}

extern "C" void kernel_launch(void* const* d_in, const int* in_sizes, int n_in,
                              void* d_out, int out_size, void* d_ws, size_t ws_size,
                              hipStream_t stream) {
    const float* q     = (const float*)d_in[0];
    const float* k     = (const float*)d_in[1];
    const float* v     = (const float*)d_in[2];
    const float* prev  = (const float*)d_in[3];
    const float* scale = (const float*)d_in[4];

    float* out  = (float*)d_out;                                   // (4,16,1024,64)
    float* wout = out  + (size_t)BSZ * NH * SL * DH;               // (4,16,1024,1024)
    float* sout = wout + (size_t)BSZ * NH * SL * SL;               // (4,16,1024,1024)

    const int nblocks = (BSZ * NH) * (SL / 16);   // 64 * 64 = 4096
    attn_fused<<<nblocks, 256, 0, stream>>>(q, k, v, prev, scale, out, wout, sout);
}

// Round 4
// 370.327 us; speedup vs baseline: 1.0537x; 1.0537x over previous
//
#include <hip/hip_runtime.h>

#define BSZ 4
#define NH 16
#define SL 1024
#define DH 64

typedef __bf16 bf16x8 __attribute__((ext_vector_type(8)));
typedef float  f32x4  __attribute__((ext_vector_type(4)));

static __device__ __forceinline__ __bf16 f2bf(float f) {
    return (__bf16)f;                          // HW RNE f32->bf16 cvt
}

static __device__ __forceinline__ void mfma16(f32x4& d, bf16x8 a, bf16x8 b) {
    d = __builtin_amdgcn_mfma_f32_16x16x32_bf16(a, b, d, 0, 0, 0);
}

// Block: 4 waves / 256 threads. Handles 16 q-rows x full 1024 s-cols of one (b,h).
// Wave w owns s in [w*256, w*256+256).
// SWAPPED QK^T: acc[t] = mfma(K_frag, Q_frag) => D[m=s][n=q]; lane l15 = q,
// regs i=0..3 = s = t*16 + 4*lhi + i  (4 CONTIGUOUS s per lane -> float4 I/O on
// prev/scores/weights, and P regs feed PV's A-fragment directly, no LDS transpose).
// NOTE: no min-waves clamp in launch_bounds — round 3 showed (256,4) caps VGPR
// at 64 and spills ~28 regs/lane (+180MB scratch traffic, 308->390us).
__global__ void __launch_bounds__(256)
attn_fused(const float* __restrict__ qg0, const float* __restrict__ kg0,
           const float* __restrict__ vg0, const float* __restrict__ pg0,
           const float* __restrict__ scale_p,
           float* __restrict__ og0, float* __restrict__ wg0, float* __restrict__ sg0)
{
    // LDS: q_s f32[16][68] @0 (4352B), aliased by o_s f32[4][16][68] @0 (17408B);
    //      red f32[2][4][16] @17408 (512B). Total 17920B.
    __shared__ __align__(16) char smem[17920];
    float (*q_s)[68]     = (float (*)[68])smem;
    float (*o_s)[16][68] = (float (*)[16][68])smem;
    float *red           = (float*)(smem + 17408);

    const int bid     = blockIdx.x;
    const int logical = (bid & 7) * 512 + (bid >> 3);   // XCD swizzle, bijective (4096%8==0)
    const int bh      = logical >> 6;                    // 64 q-tiles per (b,h)
    const int qbase   = (logical & 63) << 4;

    const int tid   = threadIdx.x;
    const int wid   = tid >> 6;
    const int lane  = tid & 63;
    const int l15   = lane & 15;
    const int lhi   = lane >> 4;
    const int sbase = wid << 8;          // this wave's s-range base

    const float scale = *scale_p;

    const float* qg = qg0 + (size_t)bh * SL * DH;
    const float* kg = kg0 + (size_t)bh * DH * SL;   // k is [d][s]
    const float* vg = vg0 + (size_t)bh * SL * DH;
    const float* pg = pg0 + (size_t)bh * SL * SL;
    float* og = og0 + (size_t)bh * SL * DH;
    float* wg = wg0 + (size_t)bh * SL * SL;
    float* sg = sg0 + (size_t)bh * SL * SL;

    // ---- stage Q tile (16x64 f32), coalesced float4 ----
    {
        const int r  = tid >> 4;
        const int c4 = (tid & 15) << 2;
        const float4 t = *(const float4*)(qg + (size_t)(qbase + r) * DH + c4);
        *(float4*)&q_s[r][c4] = t;
    }
    __syncthreads();

    // ---- Q fragments (B operand): B[k=d][n=q], lane l15 = q, k-map d ----
    bf16x8 qf[2];
#pragma unroll
    for (int ks = 0; ks < 2; ++ks)
#pragma unroll
        for (int j = 0; j < 8; ++j) {
            const int d = ks * 32 + 4 * lhi + (j & 3) + 16 * (j >> 2);
            qf[ks][j] = f2bf(q_s[l15][d]);
        }

    // ---- QK^T (swapped): acc[t][i] = S[s = sbase+t*16+4*lhi+i][q = qbase+l15] ----
    f32x4 acc[16];
#pragma unroll
    for (int t = 0; t < 16; ++t) { f32x4 z = {0.f, 0.f, 0.f, 0.f}; acc[t] = z; }

#pragma unroll
    for (int t = 0; t < 16; ++t) {
        const int s = sbase + t * 16 + l15;
#pragma unroll
        for (int ks = 0; ks < 2; ++ks) {
            bf16x8 kf;   // A[m=s][k=d], lane l15 = s
#pragma unroll
            for (int j = 0; j < 8; ++j) {
                const int d = ks * 32 + 4 * lhi + (j & 3) + 16 * (j >> 2);
                kf[j] = f2bf(kg[(size_t)d * SL + s]);   // 64B segments per 16 lanes
            }
            mfma16(acc[t], kf, qf[ks]);
        }
    }

    // ---- scores = acc*scale + prev (float4) ; write scores (float4) ----
    const int   qrow = qbase + l15;
    const float* pgr = pg + (size_t)qrow * SL;
    float*       sgr = sg + (size_t)qrow * SL;
    float*       wgr = wg + (size_t)qrow * SL;
#pragma unroll
    for (int t = 0; t < 16; ++t) {
        const int s0 = sbase + t * 16 + 4 * lhi;
        const float4 pv = *(const float4*)(pgr + s0);
        acc[t][0] = acc[t][0] * scale + pv.x;
        acc[t][1] = acc[t][1] * scale + pv.y;
        acc[t][2] = acc[t][2] * scale + pv.z;
        acc[t][3] = acc[t][3] * scale + pv.w;
        *(float4*)(sgr + s0) = make_float4(acc[t][0], acc[t][1], acc[t][2], acc[t][3]);
    }

    // ---- softmax over s (64 regs in-lane -> 2 shfl -> LDS cross-wave) ----
    float mx = acc[0][0];
#pragma unroll
    for (int t = 0; t < 16; ++t)
#pragma unroll
        for (int i = 0; i < 4; ++i) mx = fmaxf(mx, acc[t][i]);
    mx = fmaxf(mx, __shfl_xor(mx, 16, 64));
    mx = fmaxf(mx, __shfl_xor(mx, 32, 64));
    if (lhi == 0) red[wid * 16 + l15] = mx;
    __syncthreads();
    mx = fmaxf(fmaxf(red[0 + l15], red[16 + l15]),
               fmaxf(red[32 + l15], red[48 + l15]));

    float sm = 0.f;
#pragma unroll
    for (int t = 0; t < 16; ++t)
#pragma unroll
        for (int i = 0; i < 4; ++i) {
            const float p = __expf(acc[t][i] - mx);
            acc[t][i] = p;
            sm += p;
        }
    sm += __shfl_xor(sm, 16, 64);
    sm += __shfl_xor(sm, 32, 64);
    if (lhi == 0) red[64 + wid * 16 + l15] = sm;
    __syncthreads();
    const float inv = 1.f / (red[64 + l15] + red[64 + 16 + l15] +
                             red[64 + 32 + l15] + red[64 + 48 + l15]);

    // ---- weights: normalize in regs, float4 store ----
#pragma unroll
    for (int t = 0; t < 16; ++t) {
        const int s0 = sbase + t * 16 + 4 * lhi;
        acc[t][0] *= inv; acc[t][1] *= inv; acc[t][2] *= inv; acc[t][3] *= inv;
        *(float4*)(wgr + s0) = make_float4(acc[t][0], acc[t][1], acc[t][2], acc[t][3]);
    }

    // ---- PV: A-fragment comes straight from acc regs (no LDS transpose) ----
    // A[m=q][k=s]: af[j] = P[q=l15][s = sbase+ks*32+4*lhi+(j&3)+16*(j>>2)]
    //            = acc[2*ks + (j>>2)][j&3]
    f32x4 oacc[4];
#pragma unroll
    for (int nt = 0; nt < 4; ++nt) { f32x4 z = {0.f, 0.f, 0.f, 0.f}; oacc[nt] = z; }

#pragma unroll
    for (int ks = 0; ks < 8; ++ks) {
        bf16x8 af;
#pragma unroll
        for (int j = 0; j < 8; ++j) af[j] = f2bf(acc[2 * ks + (j >> 2)][j & 3]);
#pragma unroll
        for (int nt = 0; nt < 4; ++nt) {
            bf16x8 bf;   // B[k=s][n=dh], lane l15 = dh within tile nt
#pragma unroll
            for (int j = 0; j < 8; ++j) {
                const int s = sbase + ks * 32 + 4 * lhi + (j & 3) + 16 * (j >> 2);
                bf[j] = f2bf(vg[(size_t)s * DH + nt * 16 + l15]);
            }
            mfma16(oacc[nt], af, bf);
        }
    }

    // ---- cross-wave reduce of PV partials (o_s aliases q_s; q_s reads are
    //      long done — every wave passed the softmax barriers) ----
#pragma unroll
    for (int nt = 0; nt < 4; ++nt)
#pragma unroll
        for (int i = 0; i < 4; ++i)
            o_s[wid][4 * lhi + i][nt * 16 + l15] = oacc[nt][i];
    __syncthreads();
    {
        const int r  = tid >> 4;
        const int c4 = (tid & 15) << 2;
        float4 a = *(const float4*)&o_s[0][r][c4];
        const float4 b = *(const float4*)&o_s[1][r][c4];
        const float4 c = *(const float4*)&o_s[2][r][c4];
        const float4 d = *(const float4*)&o_s[3][r][c4];
        a.x += b.x + c.x + d.x;  a.y += b.y + c.y + d.y;
        a.z += b.z + c.z + d.z;  a.w += b.w + c.w + d.w;
        *(float4*)(og + (size_t)(qbase + r) * DH + c4) = a;
    }
}

extern "C" void kernel_launch(void* const* d_in, const int* in_sizes, int n_in,
                              void* d_out, int out_size, void* d_ws, size_t ws_size,
                              hipStream_t stream) {
    const float* q     = (const float*)d_in[0];
    const float* k     = (const float*)d_in[1];
    const float* v     = (const float*)d_in[2];
    const float* prev  = (const float*)d_in[3];
    const float* scale = (const float*)d_in[4];

    float* out  = (float*)d_out;                                   // (4,16,1024,64)
    float* wout = out  + (size_t)BSZ * NH * SL * DH;               // (4,16,1024,1024)
    float* sout = wout + (size_t)BSZ * NH * SL * SL;               // (4,16,1024,1024)

    const int nblocks = (BSZ * NH) * (SL / 16);   // 64 * 64 = 4096
    attn_fused<<<nblocks, 256, 0, stream>>>(q, k, v, prev, scale, out, wout, sout);
}

// Round 5
// 256.194 us; speedup vs baseline: 1.5231x; 1.4455x over previous
//
#include <hip/hip_runtime.h>

#define BSZ 4
#define NH 16
#define SL 1024
#define DH 64

typedef __bf16 bf16x8 __attribute__((ext_vector_type(8)));
typedef float  f32x4  __attribute__((ext_vector_type(4)));

static __device__ __forceinline__ __bf16 f2bf(float f) {
    return (__bf16)f;                          // HW RNE f32->bf16 cvt
}

static __device__ __forceinline__ void mfma16(f32x4& d, bf16x8 a, bf16x8 b) {
    d = __builtin_amdgcn_mfma_f32_16x16x32_bf16(a, b, d, 0, 0, 0);
}

// Block: 4 waves / 256 threads; 16 q-rows x full 1024 s-cols of one (b,h).
// Wave w owns s in [w*256, +256). Swapped QK^T: lane l15 = q, regs = 4 contig s.
// Round-5 structure: deep MLP — prev[16] float4 prefetched before QK^T,
// V software-pipelined (2x32-reg chunks) under PV MFMAs, P pre-converted to
// bf16 fragments. __launch_bounds__(256,2): 256-VGPR cap (r3 showed (256,4)
// spills; r4 showed default alloc=80 VGPR starves load batching).
__global__ void __launch_bounds__(256, 2)
attn_fused(const float* __restrict__ qg0, const float* __restrict__ kg0,
           const float* __restrict__ vg0, const float* __restrict__ pg0,
           const float* __restrict__ scale_p,
           float* __restrict__ og0, float* __restrict__ wg0, float* __restrict__ sg0)
{
    // LDS: q_s f32[16][68] @0 (4352B), aliased by o_s f32[4][16][68] @0 (17408B);
    //      red f32[2][4][16] @17408 (512B). Total 17920B.
    __shared__ __align__(16) char smem[17920];
    float (*q_s)[68]     = (float (*)[68])smem;
    float (*o_s)[16][68] = (float (*)[16][68])smem;
    float *red           = (float*)(smem + 17408);

    const int bid     = blockIdx.x;
    const int logical = (bid & 7) * 512 + (bid >> 3);   // XCD swizzle, bijective (4096%8==0)
    const int bh      = logical >> 6;                    // 64 q-tiles per (b,h)
    const int qbase   = (logical & 63) << 4;

    const int tid   = threadIdx.x;
    const int wid   = tid >> 6;
    const int lane  = tid & 63;
    const int l15   = lane & 15;
    const int lhi   = lane >> 4;
    const int sbase = wid << 8;          // this wave's s-range base

    const float scale = *scale_p;

    const float* qg = qg0 + (size_t)bh * SL * DH;
    const float* kg = kg0 + (size_t)bh * DH * SL;   // k is [d][s]
    const float* vg = vg0 + (size_t)bh * SL * DH;
    const float* pg = pg0 + (size_t)bh * SL * SL;
    float* og = og0 + (size_t)bh * SL * DH;
    float* wg = wg0 + (size_t)bh * SL * SL;
    float* sg = sg0 + (size_t)bh * SL * SL;

    const int   qrow = qbase + l15;
    const float* pgr = pg + (size_t)qrow * SL;
    float*       sgr = sg + (size_t)qrow * SL;
    float*       wgr = wg + (size_t)qrow * SL;

    // ---- stage Q tile (16x64 f32) + PREFETCH all prev (16 float4/lane) ----
    {
        const int r  = tid >> 4;
        const int c4 = (tid & 15) << 2;
        const float4 t = *(const float4*)(qg + (size_t)(qbase + r) * DH + c4);
        *(float4*)&q_s[r][c4] = t;
    }
    float4 pv[16];
#pragma unroll
    for (int t = 0; t < 16; ++t)
        pv[t] = *(const float4*)(pgr + sbase + t * 16 + 4 * lhi);   // HBM latency hides under QK^T
    __syncthreads();

    // ---- Q fragments (B operand): B[k=d][n=q], lane l15 = q ----
    bf16x8 qf[2];
#pragma unroll
    for (int ks = 0; ks < 2; ++ks)
#pragma unroll
        for (int j = 0; j < 8; ++j) {
            const int d = ks * 32 + 4 * lhi + (j & 3) + 16 * (j >> 2);
            qf[ks][j] = f2bf(q_s[l15][d]);
        }

    // ---- QK^T (swapped): acc[t][i] = S[s = sbase+t*16+4*lhi+i][q = qbase+l15] ----
    f32x4 acc[16];
#pragma unroll
    for (int t = 0; t < 16; ++t) { f32x4 z = {0.f, 0.f, 0.f, 0.f}; acc[t] = z; }

#pragma unroll
    for (int t = 0; t < 16; ++t) {
        const int s = sbase + t * 16 + l15;
#pragma unroll
        for (int ks = 0; ks < 2; ++ks) {
            bf16x8 kf;   // A[m=s][k=d], lane l15 = s (64B segments)
#pragma unroll
            for (int j = 0; j < 8; ++j) {
                const int d = ks * 32 + 4 * lhi + (j & 3) + 16 * (j >> 2);
                kf[j] = f2bf(kg[(size_t)d * SL + s]);
            }
            mfma16(acc[t], kf, qf[ks]);
        }
    }

    // ---- scores = acc*scale + prev (regs); float4 store ----
#pragma unroll
    for (int t = 0; t < 16; ++t) {
        const int s0 = sbase + t * 16 + 4 * lhi;
        acc[t][0] = acc[t][0] * scale + pv[t].x;
        acc[t][1] = acc[t][1] * scale + pv[t].y;
        acc[t][2] = acc[t][2] * scale + pv[t].z;
        acc[t][3] = acc[t][3] * scale + pv[t].w;
        *(float4*)(sgr + s0) = make_float4(acc[t][0], acc[t][1], acc[t][2], acc[t][3]);
    }

    // ---- prefetch V chunk ks=0 (32 f32/lane) — overlaps softmax ----
    float va[32], vb[32];
#pragma unroll
    for (int nt = 0; nt < 4; ++nt)
#pragma unroll
        for (int j = 0; j < 8; ++j) {
            const int s = sbase + 4 * lhi + (j & 3) + 16 * (j >> 2);
            va[nt * 8 + j] = vg[(size_t)s * DH + nt * 16 + l15];
        }

    // ---- softmax over s: 64 in-lane (4 indep chains) -> 2 shfl -> LDS ----
    float m0 = acc[0][0], m1 = acc[0][1], m2 = acc[0][2], m3 = acc[0][3];
#pragma unroll
    for (int t = 1; t < 16; ++t) {
        m0 = fmaxf(m0, acc[t][0]); m1 = fmaxf(m1, acc[t][1]);
        m2 = fmaxf(m2, acc[t][2]); m3 = fmaxf(m3, acc[t][3]);
    }
    float mx = fmaxf(fmaxf(m0, m1), fmaxf(m2, m3));
    mx = fmaxf(mx, __shfl_xor(mx, 16, 64));
    mx = fmaxf(mx, __shfl_xor(mx, 32, 64));
    if (lhi == 0) red[wid * 16 + l15] = mx;
    __syncthreads();
    mx = fmaxf(fmaxf(red[0 + l15], red[16 + l15]),
               fmaxf(red[32 + l15], red[48 + l15]));

    float s0a = 0.f, s1a = 0.f, s2a = 0.f, s3a = 0.f;
#pragma unroll
    for (int t = 0; t < 16; ++t) {
        acc[t][0] = __expf(acc[t][0] - mx); s0a += acc[t][0];
        acc[t][1] = __expf(acc[t][1] - mx); s1a += acc[t][1];
        acc[t][2] = __expf(acc[t][2] - mx); s2a += acc[t][2];
        acc[t][3] = __expf(acc[t][3] - mx); s3a += acc[t][3];
    }
    float sm = (s0a + s1a) + (s2a + s3a);
    sm += __shfl_xor(sm, 16, 64);
    sm += __shfl_xor(sm, 32, 64);
    if (lhi == 0) red[64 + wid * 16 + l15] = sm;
    __syncthreads();
    const float inv = 1.f / (red[64 + l15] + red[64 + 16 + l15] +
                             red[64 + 32 + l15] + red[64 + 48 + l15]);

    // ---- normalize in regs; float4 weights store; pre-convert P->bf16 frags ----
#pragma unroll
    for (int t = 0; t < 16; ++t) {
        const int s0 = sbase + t * 16 + 4 * lhi;
        acc[t][0] *= inv; acc[t][1] *= inv; acc[t][2] *= inv; acc[t][3] *= inv;
        *(float4*)(wgr + s0) = make_float4(acc[t][0], acc[t][1], acc[t][2], acc[t][3]);
    }
    bf16x8 paf[8];   // A[m=q][k=s]: paf[ks][j] = P[l15][sbase+ks*32+4*lhi+(j&3)+16*(j>>2)]
#pragma unroll
    for (int ks = 0; ks < 8; ++ks)
#pragma unroll
        for (int j = 0; j < 8; ++j)
            paf[ks][j] = f2bf(acc[2 * ks + (j >> 2)][j & 3]);

    // ---- PV: V double-buffered pipeline; B[k=s][n=dh], lane l15 = dh ----
    f32x4 oacc[4];
#pragma unroll
    for (int nt = 0; nt < 4; ++nt) { f32x4 z = {0.f, 0.f, 0.f, 0.f}; oacc[nt] = z; }

#pragma unroll
    for (int ks = 0; ks < 8; ++ks) {
        // issue next chunk's loads first (latency hides under this chunk's MFMAs)
        if (ks + 1 < 8) {
#pragma unroll
            for (int nt = 0; nt < 4; ++nt)
#pragma unroll
                for (int j = 0; j < 8; ++j) {
                    const int s = sbase + (ks + 1) * 32 + 4 * lhi + (j & 3) + 16 * (j >> 2);
                    if (ks & 1) va[nt * 8 + j] = vg[(size_t)s * DH + nt * 16 + l15];
                    else        vb[nt * 8 + j] = vg[(size_t)s * DH + nt * 16 + l15];
                }
        }
#pragma unroll
        for (int nt = 0; nt < 4; ++nt) {
            bf16x8 bf;
#pragma unroll
            for (int j = 0; j < 8; ++j)
                bf[j] = f2bf((ks & 1) ? vb[nt * 8 + j] : va[nt * 8 + j]);
            mfma16(oacc[nt], paf[ks], bf);
        }
    }

    // ---- cross-wave reduce of PV partials (o_s aliases q_s; safe: q_s reads
    //      finished before the softmax barriers) ----
#pragma unroll
    for (int nt = 0; nt < 4; ++nt)
#pragma unroll
        for (int i = 0; i < 4; ++i)
            o_s[wid][4 * lhi + i][nt * 16 + l15] = oacc[nt][i];
    __syncthreads();
    {
        const int r  = tid >> 4;
        const int c4 = (tid & 15) << 2;
        float4 a = *(const float4*)&o_s[0][r][c4];
        const float4 b = *(const float4*)&o_s[1][r][c4];
        const float4 c = *(const float4*)&o_s[2][r][c4];
        const float4 d = *(const float4*)&o_s[3][r][c4];
        a.x += b.x + c.x + d.x;  a.y += b.y + c.y + d.y;
        a.z += b.z + c.z + d.z;  a.w += b.w + c.w + d.w;
        *(float4*)(og + (size_t)(qbase + r) * DH + c4) = a;
    }
}

extern "C" void kernel_launch(void* const* d_in, const int* in_sizes, int n_in,
                              void* d_out, int out_size, void* d_ws, size_t ws_size,
                              hipStream_t stream) {
    const float* q     = (const float*)d_in[0];
    const float* k     = (const float*)d_in[1];
    const float* v     = (const float*)d_in[2];
    const float* prev  = (const float*)d_in[3];
    const float* scale = (const float*)d_in[4];

    float* out  = (float*)d_out;                                   // (4,16,1024,64)
    float* wout = out  + (size_t)BSZ * NH * SL * DH;               // (4,16,1024,1024)
    float* sout = wout + (size_t)BSZ * NH * SL * SL;               // (4,16,1024,1024)

    const int nblocks = (BSZ * NH) * (SL / 16);   // 64 * 64 = 4096
    attn_fused<<<nblocks, 256, 0, stream>>>(q, k, v, prev, scale, out, wout, sout);
}